// Round 2
// baseline (4053.489 us; speedup 1.0000x reference)
//
#include <hip/hip_runtime.h>
#include <cstdint>
#include <cstdio>

// CustomLSTM: B=64, T=512, D=H=1024.  f16 MFMA pipeline:
//   k_init    : h0 -> tagged h word buffer (parity0 tag=0, parity1 tag=0xFFFF)
//   k_castx   : input_seq fp32 -> f16
//   k_weights : build permuted f16 Wi[4096][1024], Wh[4096][1024]
//               row perm p = nb*64 + uu*4 + gate
//   k_gemm    : x_proj[32768][4096] f16 = X @ Wi^T   (128x128 tile, mfma 16x16x32)
//   k_rnn     : persistent scan, 256 WGs (1/CU), Wh slice in LDS.
//               R4 sync: SELF-VALIDATING h words. Each h is stored as
//               {tag=epoch:16 | h_f16:16} in a ping-pong (by epoch parity)
//               buffer. The consumer's h load IS the poll: load 64 words/lane,
//               check tags==t via v_perm+xor, reload until fresh. This removes
//               the entire flag protocol from the critical path:
//                 - no vmcnt(0) store drain
//                 - no flag store / flag propagate round
//                 - no flag-poll -> h-load serialization (was a 4th round trip)
//               Safety: WG stores epoch e+2 only after its top-poll saw tag
//               e+1 on ALL 64 producers' words (union over 4 waves + mid
//               __syncthreads); a producer publishing e+1 has completed its
//               epoch-e loads. Hence 2 parity buffers suffice. k_init fully
//               rewrites both parities each launch (graph replay safe).

typedef _Float16 half8 __attribute__((ext_vector_type(8)));
typedef _Float16 half4 __attribute__((ext_vector_type(4)));
typedef float f32x4 __attribute__((ext_vector_type(4)));

typedef __attribute__((address_space(1))) uint32_t gu32;
typedef __attribute__((address_space(3))) uint32_t lu32;

#define MFMA16(a, b, c) __builtin_amdgcn_mfma_f32_16x16x32_f16((a), (b), (c), 0, 0, 0)

// workspace layout (bytes)
#define XP_OFF   0ull                 // x_proj f16 [32768][4096]  = 256 MB
#define AH_OFF   268435456ull         // input f16  [32768][1024]  =  64 MB
#define WI_OFF   335544320ull         // Wi_perm f16 [4096][1024]  =   8 MB
#define WH_OFF   343932928ull         // Wh_perm f16 [4096][1024]  =   8 MB
#define THB_OFF  352321536ull         // tagged h words [2][64][1024] u32 = 512 KB
#define WS_NEED  352845824ull

#define RED_STRIDE 68                 // reduction row stride (floats), 16B-aligned

__device__ inline float sigmoid_f(float x) { return 1.f / (1.f + __expf(-x)); }
__device__ inline float tanh_f(float x) {
  float ax = fabsf(x);
  float e = __expf(-2.f * ax);          // in (0,1], no overflow
  float t = (1.f - e) / (1.f + e);
  return x < 0.f ? -t : t;
}

// 256 blocks x 256 thr: i covers 65536 = 64*1024 units
__global__ void k_init(const float* __restrict__ h0, uint32_t* __restrict__ thb) {
  int i = blockIdx.x * 256 + threadIdx.x;
  unsigned short hb = __builtin_bit_cast(unsigned short, (_Float16)h0[i]);
  thb[i] = (uint32_t)hb;                // parity 0: tag 0 | h0
  thb[65536 + i] = 0xFFFF0000u;         // parity 1: tag 0xFFFF (never matches)
}

__global__ void k_castx(const float* __restrict__ x, _Float16* __restrict__ xh) {
  size_t i = ((size_t)blockIdx.x * 256 + threadIdx.x) * 8;
  float4 a = *(const float4*)(x + i);
  float4 b = *(const float4*)(x + i + 4);
  half8 o = {(_Float16)a.x, (_Float16)a.y, (_Float16)a.z, (_Float16)a.w,
             (_Float16)b.x, (_Float16)b.y, (_Float16)b.z, (_Float16)b.w};
  *(half8*)(xh + i) = o;
}

// 8192 blocks: 0..4095 -> Wi rows, 4096..8191 -> Wh rows. 256 thr x 4 cols.
// perm row p = nb*64 + uu*4 + gate
__global__ void k_weights(const float* __restrict__ Wii, const float* __restrict__ Wif,
                          const float* __restrict__ Wig, const float* __restrict__ Wio,
                          const float* __restrict__ Whi, const float* __restrict__ Whf,
                          const float* __restrict__ Whg, const float* __restrict__ Who,
                          _Float16* __restrict__ WI, _Float16* __restrict__ WH) {
  int r = blockIdx.x;
  int p = r & 4095;
  int nb = p >> 6, uu = (p >> 2) & 15, gi = p & 3;
  int srow = nb * 16 + uu;
  const float* src;
  if (r < 4096) src = (gi == 0 ? Wii : gi == 1 ? Wif : gi == 2 ? Wig : Wio);
  else          src = (gi == 0 ? Whi : gi == 1 ? Whf : gi == 2 ? Whg : Who);
  src += (size_t)srow * 1024;
  _Float16* dst = (r < 4096 ? WI : WH) + (size_t)p * 1024;
  int c = threadIdx.x * 4;
  float4 v = *(const float4*)(src + c);
  half4 o = {(_Float16)v.x, (_Float16)v.y, (_Float16)v.z, (_Float16)v.w};
  *(half4*)(dst + c) = o;
}

// x_proj = A[32768][1024] @ B[4096][1024]^T, f16 out. 128x128 tile, BK=32.
__global__ __launch_bounds__(256) void k_gemm(const _Float16* __restrict__ A,
                                              const _Float16* __restrict__ B,
                                              _Float16* __restrict__ XPo) {
  __shared__ __align__(16) _Float16 As[128 * 32];
  __shared__ __align__(16) _Float16 Bs[128 * 32];
  const int tid = threadIdx.x;
  const int w = tid >> 6, l = tid & 63;
  const int wm = w >> 1, wn = w & 1;
  const int lm = l & 15, lq = l >> 4;
  const size_t m0 = (size_t)blockIdx.x * 128;
  const size_t n0 = (size_t)blockIdx.y * 128;

  f32x4 acc[4][4] = {};

  // staging: slot s (0..511) -> LDS bytes s*16; row = s>>2, kchunk = s&3
  const int r0 = tid >> 2, c0_ = tid & 3;
  const int r1 = (256 + tid) >> 2, c1_ = tid & 3;
  const _Float16* ga0 = A + (m0 + r0) * 1024 + c0_ * 8;
  const _Float16* ga1 = A + (m0 + r1) * 1024 + c1_ * 8;
  const _Float16* gb0 = B + (n0 + r0) * 1024 + c0_ * 8;
  const _Float16* gb1 = B + (n0 + r1) * 1024 + c1_ * 8;
  _Float16* laBase = As + (size_t)w * 512;   // wave-uniform LDS base (+lane*16 by HW)
  _Float16* lbBase = Bs + (size_t)w * 512;

  for (int kt = 0; kt < 32; ++kt) {
    const int k0 = kt * 32;
    __syncthreads();
    __builtin_amdgcn_global_load_lds((gu32*)(ga0 + k0), (lu32*)laBase, 16, 0, 0);
    __builtin_amdgcn_global_load_lds((gu32*)(ga1 + k0), (lu32*)(laBase + 2048), 16, 0, 0);
    __builtin_amdgcn_global_load_lds((gu32*)(gb0 + k0), (lu32*)lbBase, 16, 0, 0);
    __builtin_amdgcn_global_load_lds((gu32*)(gb1 + k0), (lu32*)(lbBase + 2048), 16, 0, 0);
    __syncthreads();

    half8 af[4], bf[4];
#pragma unroll
    for (int mi = 0; mi < 4; ++mi)
      af[mi] = *(const half8*)(As + (size_t)(wm * 64 + mi * 16 + lm) * 32 + lq * 8);
#pragma unroll
    for (int ni = 0; ni < 4; ++ni)
      bf[ni] = *(const half8*)(Bs + (size_t)(wn * 64 + ni * 16 + lm) * 32 + lq * 8);
#pragma unroll
    for (int mi = 0; mi < 4; ++mi)
#pragma unroll
      for (int ni = 0; ni < 4; ++ni)
        acc[mi][ni] = MFMA16(af[mi], bf[ni], acc[mi][ni]);
  }

#pragma unroll
  for (int mi = 0; mi < 4; ++mi) {
#pragma unroll
    for (int r = 0; r < 4; ++r) {
      size_t m = m0 + wm * 64 + mi * 16 + lq * 4 + r;  // D row=(l>>4)*4+r, col=l&15
      _Float16* orow = XPo + m * 4096 + n0 + wn * 64 + lm;
#pragma unroll
      for (int ni = 0; ni < 4; ++ni) orow[ni * 16] = (_Float16)acc[mi][ni][r];
    }
  }
}

// Persistent scan. WG = (mb = bid&3: 16 batches, nb = bid>>2: 16 units).
__global__ __launch_bounds__(256, 1) void k_rnn(
    const _Float16* __restrict__ XP, const _Float16* __restrict__ WH,
    const float* __restrict__ c0,
    const float* __restrict__ bI, const float* __restrict__ bF,
    const float* __restrict__ bG, const float* __restrict__ bO,
    uint32_t* __restrict__ thb, float* __restrict__ out) {
  __shared__ __align__(16) char smem[131072 + RED_STRIDE * 64 * 4];
  _Float16* wl = (_Float16*)smem;         // Wh slice swizzled [kc=128][row=64][8]
  float* red = (float*)(smem + 131072);   // [wave*16+batch][RED_STRIDE]

  const int tid = threadIdx.x;
  const int mb = blockIdx.x & 3;
  const int nb = blockIdx.x >> 2;

  // fill Wh LDS: slot s -> bytes s*16, row = s&63, kc = s>>6 (conflict-free writes)
  const _Float16* wsrc = WH + (size_t)nb * 64 * 1024;
#pragma unroll 4
  for (int it = 0; it < 32; ++it) {
    int s = it * 256 + tid;
    int row = s & 63, kc = s >> 6;
    *(half8*)(wl + (size_t)s * 8) = *(const half8*)(wsrc + (size_t)row * 1024 + kc * 8);
  }

  const int w = tid >> 6, l = tid & 63;
  const int lm = l & 15, lq = l >> 4;
  const int bl = tid >> 4, uu = tid & 15;
  const int bgrow = mb * 16 + bl;   // global batch (finalize role)
  const int u = nb * 16 + uu;       // global unit  (finalize role)

  float c = c0[(size_t)bgrow * 1024 + u];
  const float bias0 = bI[u], bias1 = bF[u], bias2 = bG[u], bias3 = bO[u];
  // interleaved-gate XP base: cols nb*64 + uu*4 + {0,1,2,3}
  const size_t xpth = (size_t)bgrow * 512 * 4096 + (size_t)nb * 64 + (size_t)uu * 4;

  // consumer word base: batch (mb*16+lm), units [w*256 + lq*8 + kk*32, +8)
  const size_t habase = (size_t)(mb * 16 + lm) * 1024 + (size_t)lq * 8 + (size_t)w * 256;
  // producer word address (this thread's (bgrow, u) h)
  const size_t hstw = (size_t)bgrow * 1024 + u;

  // prefetch step-0 x_proj contributions (4 contiguous f16)
  half4 xn = *(const half4*)(XP + xpth);

  __syncthreads();

  for (int t = 0; t < 512; ++t) {
    const float xv0 = (float)xn[0], xv1 = (float)xn[1];
    const float xv2 = (float)xn[2], xv3 = (float)xn[3];

    // ---- tagged h load == poll: reload until all 64 tags equal t ----
    const uint64_t* hq =
        (const uint64_t*)(thb + (size_t)(t & 1) * 65536 + habase);
    uint64_t hraw[32];
    const uint32_t expt = (uint32_t)t * 0x00010001u;   // t | t<<16
    for (;;) {
#pragma unroll
      for (int kk = 0; kk < 8; ++kk)
#pragma unroll
        for (int j = 0; j < 4; ++j)
          hraw[4 * kk + j] = __hip_atomic_load(hq + (size_t)kk * 16 + j,
                                               __ATOMIC_RELAXED,
                                               __HIP_MEMORY_SCOPE_AGENT);
      uint32_t bad = 0;
#pragma unroll
      for (int i = 0; i < 32; ++i)
        bad |= __builtin_amdgcn_perm((uint32_t)(hraw[i] >> 32),
                                     (uint32_t)hraw[i], 0x07060302u) ^ expt;
      if (!__any(bad != 0)) break;
    }

    // ---- gates partial: wave w covers k in [w*256, w*256+256) ----
    f32x4 a0 = {0.f, 0.f, 0.f, 0.f}, a1 = a0, a2 = a0, a3 = a0;
#pragma unroll
    for (int kk = 0; kk < 8; ++kk) {
      union { uint32_t u[4]; half8 v; } av;
#pragma unroll
      for (int j = 0; j < 4; ++j) {
        uint64_t q = hraw[4 * kk + j];
        av.u[j] = __builtin_amdgcn_perm((uint32_t)(q >> 32), (uint32_t)q,
                                        0x05040100u);   // pack 2 low halves
      }
      const int k0 = w * 256 + kk * 32;
      const _Float16* bb = wl + (size_t)(k0 / 8 + lq) * 512 + lm * 8;
      a0 = MFMA16(av.v, *(const half8*)(bb), a0);
      a1 = MFMA16(av.v, *(const half8*)(bb + 128), a1);
      a2 = MFMA16(av.v, *(const half8*)(bb + 256), a2);
      a3 = MFMA16(av.v, *(const half8*)(bb + 384), a3);
    }
#pragma unroll
    for (int r = 0; r < 4; ++r) {   // D: row=(l>>4)*4+r (batch), col=l&15
      float* rr = red + (size_t)(w * 16 + lq * 4 + r) * RED_STRIDE + lm;
      rr[0] = a0[r]; rr[16] = a1[r]; rr[32] = a2[r]; rr[48] = a3[r];
    }
    __syncthreads();

    // ---- finalize: thread = (batch bl, unit uu); gates at cols uu*4+g ----
    float p0 = xv0 + bias0, p1 = xv1 + bias1, p2 = xv2 + bias2, p3 = xv3 + bias3;
#pragma unroll
    for (int ww = 0; ww < 4; ++ww) {
      const float4 v = *(const float4*)(red + (size_t)(ww * 16 + bl) * RED_STRIDE + uu * 4);
      p0 += v.x; p1 += v.y; p2 += v.z; p3 += v.w;
    }
    float ig = sigmoid_f(p0), fg = sigmoid_f(p1), gg = tanh_f(p2), og = sigmoid_f(p3);
    c = fg * c + ig * gg;
    float h = og * tanh_f(c);

    if (t < 511) {
      // fire-and-forget tagged h store: {tag=t+1 | h}; no drain, no flag
      uint32_t word = ((uint32_t)(t + 1) << 16) |
                      (uint32_t)__builtin_bit_cast(unsigned short, (_Float16)h);
      __hip_atomic_store(thb + (size_t)((t + 1) & 1) * 65536 + hstw, word,
                         __ATOMIC_RELAXED, __HIP_MEMORY_SCOPE_AGENT);

      // overlap with other WGs' polling: out store + next-step XP prefetch
      out[(size_t)(bgrow * 512 + t) * 1024 + u] = h;
      xn = *(const half4*)(XP + xpth + (size_t)(t + 1) * 4096);

      // red reuse fence: prev finalize reads done before next red writes
      __syncthreads();
    } else {
      out[(size_t)(bgrow * 512 + t) * 1024 + u] = h;
      out[33554432u + (size_t)bgrow * 1024 + u] = h;
      out[33554432u + 65536u + (size_t)bgrow * 1024 + u] = c;
    }
  }
}

extern "C" void kernel_launch(void* const* d_in, const int* in_sizes, int n_in,
                              void* d_out, int out_size, void* d_ws, size_t ws_size,
                              hipStream_t stream) {
  const float* x   = (const float*)d_in[0];
  const float* h0  = (const float*)d_in[1];
  const float* c0  = (const float*)d_in[2];
  const float* Wii = (const float*)d_in[3];
  const float* Whi = (const float*)d_in[4];
  const float* bI  = (const float*)d_in[5];
  const float* Wif = (const float*)d_in[6];
  const float* Whf = (const float*)d_in[7];
  const float* bF  = (const float*)d_in[8];
  const float* Wig = (const float*)d_in[9];
  const float* Whg = (const float*)d_in[10];
  const float* bG  = (const float*)d_in[11];
  const float* Wio = (const float*)d_in[12];
  const float* Who = (const float*)d_in[13];
  const float* bO  = (const float*)d_in[14];
  float* out = (float*)d_out;

  if (ws_size < WS_NEED) {
    fprintf(stderr, "kernel_launch: ws too small (%zu < %llu)\n", ws_size,
            (unsigned long long)WS_NEED);
    return;
  }
  char* ws = (char*)d_ws;
  _Float16* XP  = (_Float16*)(ws + XP_OFF);
  _Float16* AH  = (_Float16*)(ws + AH_OFF);
  _Float16* WI  = (_Float16*)(ws + WI_OFF);
  _Float16* WH  = (_Float16*)(ws + WH_OFF);
  uint32_t* THB = (uint32_t*)(ws + THB_OFF);

  k_init<<<256, 256, 0, stream>>>(h0, THB);
  k_castx<<<16384, 256, 0, stream>>>(x, AH);
  k_weights<<<8192, 256, 0, stream>>>(Wii, Wif, Wig, Wio, Whi, Whf, Whg, Who, WI, WH);
  k_gemm<<<dim3(256, 32), 256, 0, stream>>>(AH, WI, XP);
  k_rnn<<<256, 256, 0, stream>>>(XP, WH, c0, bI, bF, bG, bO, THB, out);
}

// Round 3
// 3391.428 us; speedup vs baseline: 1.1952x; 1.1952x over previous
//
#include <hip/hip_runtime.h>
#include <cstdint>
#include <cstdio>

// CustomLSTM: B=64, T=512, D=H=1024.  f16 MFMA pipeline:
//   k_init    : h0 -> tagged h word buffer (parity0 tag=0, parity1 tag=0xFFFF)
//   k_castx   : input_seq fp32 -> f16
//   k_weights : build permuted f16 Wi[4096][1024], Wh[4096][1024]
//               row perm p = nb*64 + uu*4 + gate
//   k_gemm    : x_proj[32768][4096] f16 = X @ Wi^T   (128x128 tile, mfma 16x16x32)
//   k_rnn     : persistent scan, 256 WGs (1/CU), Wh slice in LDS.
//               R5 sync (hybrid of R3+R4, keeping what each got right):
//                 - h words are tagged {epoch:16 | h_f16:16}, ping-pong by
//                   epoch parity. Producer publish = the h store itself:
//                   NO vmcnt(0) drain, NO flag store, NO flag round trip.
//                   Producer also reaches its next step sooner (less straggler
//                   lag for everyone else).
//                 - detect stays CHEAP (R4's mistake was poll-by-bulk-reload):
//                   per-wave sentinel poll, 1 u32/lane = one data word of each
//                   of this wave's 16 producers (4 lanes per producer).
//                 - after sentinels pass: ONE bulk tagged load (32x8B/lane),
//                   per-word tag check via v_perm+xor; whole-wave retry only
//                   in the rare OOO-visibility window.
//               Safety: WG stores epoch t+1 only after all 4 waves validated
//               per-word ALL 64 producers' words at tag t (mid __syncthreads
//               joins the union); a producer publishing tag t has completed
//               its epoch t-1 reads. Hence 2 parity buffers suffice. k_init
//               fully rewrites both parities each launch (graph replay safe).

typedef _Float16 half8 __attribute__((ext_vector_type(8)));
typedef _Float16 half4 __attribute__((ext_vector_type(4)));
typedef float f32x4 __attribute__((ext_vector_type(4)));

typedef __attribute__((address_space(1))) uint32_t gu32;
typedef __attribute__((address_space(3))) uint32_t lu32;

#define MFMA16(a, b, c) __builtin_amdgcn_mfma_f32_16x16x32_f16((a), (b), (c), 0, 0, 0)

// workspace layout (bytes)
#define XP_OFF   0ull                 // x_proj f16 [32768][4096]  = 256 MB
#define AH_OFF   268435456ull         // input f16  [32768][1024]  =  64 MB
#define WI_OFF   335544320ull         // Wi_perm f16 [4096][1024]  =   8 MB
#define WH_OFF   343932928ull         // Wh_perm f16 [4096][1024]  =   8 MB
#define THB_OFF  352321536ull         // tagged h words [2][64][1024] u32 = 512 KB
#define WS_NEED  352845824ull

#define RED_STRIDE 68                 // reduction row stride (floats), 16B-aligned

__device__ inline float sigmoid_f(float x) { return 1.f / (1.f + __expf(-x)); }
__device__ inline float tanh_f(float x) {
  float ax = fabsf(x);
  float e = __expf(-2.f * ax);          // in (0,1], no overflow
  float t = (1.f - e) / (1.f + e);
  return x < 0.f ? -t : t;
}

// 256 blocks x 256 thr: i covers 65536 = 64*1024 units
__global__ void k_init(const float* __restrict__ h0, uint32_t* __restrict__ thb) {
  int i = blockIdx.x * 256 + threadIdx.x;
  unsigned short hb = __builtin_bit_cast(unsigned short, (_Float16)h0[i]);
  thb[i] = (uint32_t)hb;                // parity 0: tag 0 | h0
  thb[65536 + i] = 0xFFFF0000u;         // parity 1: tag 0xFFFF (never matches)
}

__global__ void k_castx(const float* __restrict__ x, _Float16* __restrict__ xh) {
  size_t i = ((size_t)blockIdx.x * 256 + threadIdx.x) * 8;
  float4 a = *(const float4*)(x + i);
  float4 b = *(const float4*)(x + i + 4);
  half8 o = {(_Float16)a.x, (_Float16)a.y, (_Float16)a.z, (_Float16)a.w,
             (_Float16)b.x, (_Float16)b.y, (_Float16)b.z, (_Float16)b.w};
  *(half8*)(xh + i) = o;
}

// 8192 blocks: 0..4095 -> Wi rows, 4096..8191 -> Wh rows. 256 thr x 4 cols.
// perm row p = nb*64 + uu*4 + gate
__global__ void k_weights(const float* __restrict__ Wii, const float* __restrict__ Wif,
                          const float* __restrict__ Wig, const float* __restrict__ Wio,
                          const float* __restrict__ Whi, const float* __restrict__ Whf,
                          const float* __restrict__ Whg, const float* __restrict__ Who,
                          _Float16* __restrict__ WI, _Float16* __restrict__ WH) {
  int r = blockIdx.x;
  int p = r & 4095;
  int nb = p >> 6, uu = (p >> 2) & 15, gi = p & 3;
  int srow = nb * 16 + uu;
  const float* src;
  if (r < 4096) src = (gi == 0 ? Wii : gi == 1 ? Wif : gi == 2 ? Wig : Wio);
  else          src = (gi == 0 ? Whi : gi == 1 ? Whf : gi == 2 ? Whg : Who);
  src += (size_t)srow * 1024;
  _Float16* dst = (r < 4096 ? WI : WH) + (size_t)p * 1024;
  int c = threadIdx.x * 4;
  float4 v = *(const float4*)(src + c);
  half4 o = {(_Float16)v.x, (_Float16)v.y, (_Float16)v.z, (_Float16)v.w};
  *(half4*)(dst + c) = o;
}

// x_proj = A[32768][1024] @ B[4096][1024]^T, f16 out. 128x128 tile, BK=32.
__global__ __launch_bounds__(256) void k_gemm(const _Float16* __restrict__ A,
                                              const _Float16* __restrict__ B,
                                              _Float16* __restrict__ XPo) {
  __shared__ __align__(16) _Float16 As[128 * 32];
  __shared__ __align__(16) _Float16 Bs[128 * 32];
  const int tid = threadIdx.x;
  const int w = tid >> 6, l = tid & 63;
  const int wm = w >> 1, wn = w & 1;
  const int lm = l & 15, lq = l >> 4;
  const size_t m0 = (size_t)blockIdx.x * 128;
  const size_t n0 = (size_t)blockIdx.y * 128;

  f32x4 acc[4][4] = {};

  // staging: slot s (0..511) -> LDS bytes s*16; row = s>>2, kchunk = s&3
  const int r0 = tid >> 2, c0_ = tid & 3;
  const int r1 = (256 + tid) >> 2, c1_ = tid & 3;
  const _Float16* ga0 = A + (m0 + r0) * 1024 + c0_ * 8;
  const _Float16* ga1 = A + (m0 + r1) * 1024 + c1_ * 8;
  const _Float16* gb0 = B + (n0 + r0) * 1024 + c0_ * 8;
  const _Float16* gb1 = B + (n0 + r1) * 1024 + c1_ * 8;
  _Float16* laBase = As + (size_t)w * 512;   // wave-uniform LDS base (+lane*16 by HW)
  _Float16* lbBase = Bs + (size_t)w * 512;

  for (int kt = 0; kt < 32; ++kt) {
    const int k0 = kt * 32;
    __syncthreads();
    __builtin_amdgcn_global_load_lds((gu32*)(ga0 + k0), (lu32*)laBase, 16, 0, 0);
    __builtin_amdgcn_global_load_lds((gu32*)(ga1 + k0), (lu32*)(laBase + 2048), 16, 0, 0);
    __builtin_amdgcn_global_load_lds((gu32*)(gb0 + k0), (lu32*)lbBase, 16, 0, 0);
    __builtin_amdgcn_global_load_lds((gu32*)(gb1 + k0), (lu32*)(lbBase + 2048), 16, 0, 0);
    __syncthreads();

    half8 af[4], bf[4];
#pragma unroll
    for (int mi = 0; mi < 4; ++mi)
      af[mi] = *(const half8*)(As + (size_t)(wm * 64 + mi * 16 + lm) * 32 + lq * 8);
#pragma unroll
    for (int ni = 0; ni < 4; ++ni)
      bf[ni] = *(const half8*)(Bs + (size_t)(wn * 64 + ni * 16 + lm) * 32 + lq * 8);
#pragma unroll
    for (int mi = 0; mi < 4; ++mi)
#pragma unroll
      for (int ni = 0; ni < 4; ++ni)
        acc[mi][ni] = MFMA16(af[mi], bf[ni], acc[mi][ni]);
  }

#pragma unroll
  for (int mi = 0; mi < 4; ++mi) {
#pragma unroll
    for (int r = 0; r < 4; ++r) {
      size_t m = m0 + wm * 64 + mi * 16 + lq * 4 + r;  // D row=(l>>4)*4+r, col=l&15
      _Float16* orow = XPo + m * 4096 + n0 + wn * 64 + lm;
#pragma unroll
      for (int ni = 0; ni < 4; ++ni) orow[ni * 16] = (_Float16)acc[mi][ni][r];
    }
  }
}

// Persistent scan. WG = (mb = bid&3: 16 batches, nb = bid>>2: 16 units).
__global__ __launch_bounds__(256, 1) void k_rnn(
    const _Float16* __restrict__ XP, const _Float16* __restrict__ WH,
    const float* __restrict__ c0,
    const float* __restrict__ bI, const float* __restrict__ bF,
    const float* __restrict__ bG, const float* __restrict__ bO,
    uint32_t* __restrict__ thb, float* __restrict__ out) {
  __shared__ __align__(16) char smem[131072 + RED_STRIDE * 64 * 4];
  _Float16* wl = (_Float16*)smem;         // Wh slice swizzled [kc=128][row=64][8]
  float* red = (float*)(smem + 131072);   // [wave*16+batch][RED_STRIDE]

  const int tid = threadIdx.x;
  const int mb = blockIdx.x & 3;
  const int nb = blockIdx.x >> 2;

  // fill Wh LDS: slot s -> bytes s*16, row = s&63, kc = s>>6 (conflict-free writes)
  const _Float16* wsrc = WH + (size_t)nb * 64 * 1024;
#pragma unroll 4
  for (int it = 0; it < 32; ++it) {
    int s = it * 256 + tid;
    int row = s & 63, kc = s >> 6;
    *(half8*)(wl + (size_t)s * 8) = *(const half8*)(wsrc + (size_t)row * 1024 + kc * 8);
  }

  const int w = tid >> 6, l = tid & 63;
  const int lm = l & 15, lq = l >> 4;
  const int bl = tid >> 4, uu = tid & 15;
  const int bgrow = mb * 16 + bl;   // global batch (finalize role)
  const int u = nb * 16 + uu;       // global unit  (finalize role)

  float c = c0[(size_t)bgrow * 1024 + u];
  const float bias0 = bI[u], bias1 = bF[u], bias2 = bG[u], bias3 = bO[u];
  // interleaved-gate XP base: cols nb*64 + uu*4 + {0,1,2,3}
  const size_t xpth = (size_t)bgrow * 512 * 4096 + (size_t)nb * 64 + (size_t)uu * 4;

  // consumer bulk base (u32 units): batch (mb*16+lm), units w*256 + lq*8 (+kk*32)
  const size_t habase = (size_t)(mb * 16 + lm) * 1024 + (size_t)lq * 8 + (size_t)w * 256;
  // sentinel: lane l -> producer nb' = w*16 + (l>>2), batch row mb*16 + (l&3),
  // first unit of that producer's range (a real data word, written by its pair store)
  const size_t sentoff = (size_t)(mb * 16 + (l & 3)) * 1024 + (size_t)(w * 16 + (l >> 2)) * 16;
  // producer word index (this thread's (bgrow, u) h)
  const size_t hstw = (size_t)bgrow * 1024 + u;

  // prefetch step-0 x_proj contributions (4 contiguous f16)
  half4 xn = *(const half4*)(XP + xpth);

  __syncthreads();

  for (int t = 0; t < 512; ++t) {
    const float xv0 = (float)xn[0], xv1 = (float)xn[1];
    const float xv2 = (float)xn[2], xv3 = (float)xn[3];

    const uint32_t* b32 = thb + (size_t)(t & 1) * 65536;

    // ---- sentinel poll: 1 u32/lane, this wave's 16 producers only ----
    {
      uint32_t sv;
      do {
        sv = __hip_atomic_load(b32 + sentoff, __ATOMIC_RELAXED,
                               __HIP_MEMORY_SCOPE_AGENT);
      } while (__any((sv >> 16) != (uint32_t)t));
    }

    // ---- bulk tagged load + per-word check (retry rare: OOO window) ----
    const uint64_t* hq = (const uint64_t*)(b32 + habase);
    uint64_t hraw[32];
    const uint32_t expt = (uint32_t)t * 0x00010001u;   // t | t<<16
    for (;;) {
#pragma unroll
      for (int kk = 0; kk < 8; ++kk)
#pragma unroll
        for (int j = 0; j < 4; ++j)
          hraw[4 * kk + j] = __hip_atomic_load(hq + (size_t)kk * 16 + j,
                                               __ATOMIC_RELAXED,
                                               __HIP_MEMORY_SCOPE_AGENT);
      uint32_t bad = 0;
#pragma unroll
      for (int i = 0; i < 32; ++i)
        bad |= __builtin_amdgcn_perm((uint32_t)(hraw[i] >> 32),
                                     (uint32_t)hraw[i], 0x07060302u) ^ expt;
      if (!__any(bad != 0)) break;
    }

    // ---- gates partial: wave w covers k in [w*256, w*256+256) ----
    f32x4 a0 = {0.f, 0.f, 0.f, 0.f}, a1 = a0, a2 = a0, a3 = a0;
#pragma unroll
    for (int kk = 0; kk < 8; ++kk) {
      union { uint32_t u[4]; half8 v; } av;
#pragma unroll
      for (int j = 0; j < 4; ++j) {
        uint64_t q = hraw[4 * kk + j];
        av.u[j] = __builtin_amdgcn_perm((uint32_t)(q >> 32), (uint32_t)q,
                                        0x05040100u);   // pack 2 low halves
      }
      const int k0 = w * 256 + kk * 32;
      const _Float16* bb = wl + (size_t)(k0 / 8 + lq) * 512 + lm * 8;
      a0 = MFMA16(av.v, *(const half8*)(bb), a0);
      a1 = MFMA16(av.v, *(const half8*)(bb + 128), a1);
      a2 = MFMA16(av.v, *(const half8*)(bb + 256), a2);
      a3 = MFMA16(av.v, *(const half8*)(bb + 384), a3);
    }
#pragma unroll
    for (int r = 0; r < 4; ++r) {   // D: row=(l>>4)*4+r (batch), col=l&15
      float* rr = red + (size_t)(w * 16 + lq * 4 + r) * RED_STRIDE + lm;
      rr[0] = a0[r]; rr[16] = a1[r]; rr[32] = a2[r]; rr[48] = a3[r];
    }
    __syncthreads();

    // ---- finalize: thread = (batch bl, unit uu); gates at cols uu*4+g ----
    float p0 = xv0 + bias0, p1 = xv1 + bias1, p2 = xv2 + bias2, p3 = xv3 + bias3;
#pragma unroll
    for (int ww = 0; ww < 4; ++ww) {
      const float4 v = *(const float4*)(red + (size_t)(ww * 16 + bl) * RED_STRIDE + uu * 4);
      p0 += v.x; p1 += v.y; p2 += v.z; p3 += v.w;
    }
    float ig = sigmoid_f(p0), fg = sigmoid_f(p1), gg = tanh_f(p2), og = sigmoid_f(p3);
    c = fg * c + ig * gg;
    float h = og * tanh_f(c);

    if (t < 511) {
      // publish = tagged h store (pairs of u32 via 1 shfl); no drain, no flag
      uint32_t word = ((uint32_t)(t + 1) << 16) |
                      (uint32_t)__builtin_bit_cast(unsigned short, (_Float16)h);
      uint32_t other = (uint32_t)__shfl_xor((int)word, 1, 64);
      if ((uu & 1) == 0) {
        uint64_t q = (uint64_t)word | ((uint64_t)other << 32);
        __hip_atomic_store((uint64_t*)(thb + (size_t)((t + 1) & 1) * 65536) +
                               (hstw >> 1),
                           q, __ATOMIC_RELAXED, __HIP_MEMORY_SCOPE_AGENT);
      }

      // overlap with other WGs' polling: out store + next-step XP prefetch
      out[(size_t)(bgrow * 512 + t) * 1024 + u] = h;
      xn = *(const half4*)(XP + xpth + (size_t)(t + 1) * 4096);

      // red reuse fence: prev finalize reads done before next red writes
      __syncthreads();
    } else {
      out[(size_t)(bgrow * 512 + t) * 1024 + u] = h;
      out[33554432u + (size_t)bgrow * 1024 + u] = h;
      out[33554432u + 65536u + (size_t)bgrow * 1024 + u] = c;
    }
  }
}

extern "C" void kernel_launch(void* const* d_in, const int* in_sizes, int n_in,
                              void* d_out, int out_size, void* d_ws, size_t ws_size,
                              hipStream_t stream) {
  const float* x   = (const float*)d_in[0];
  const float* h0  = (const float*)d_in[1];
  const float* c0  = (const float*)d_in[2];
  const float* Wii = (const float*)d_in[3];
  const float* Whi = (const float*)d_in[4];
  const float* bI  = (const float*)d_in[5];
  const float* Wif = (const float*)d_in[6];
  const float* Whf = (const float*)d_in[7];
  const float* bF  = (const float*)d_in[8];
  const float* Wig = (const float*)d_in[9];
  const float* Whg = (const float*)d_in[10];
  const float* bG  = (const float*)d_in[11];
  const float* Wio = (const float*)d_in[12];
  const float* Who = (const float*)d_in[13];
  const float* bO  = (const float*)d_in[14];
  float* out = (float*)d_out;

  if (ws_size < WS_NEED) {
    fprintf(stderr, "kernel_launch: ws too small (%zu < %llu)\n", ws_size,
            (unsigned long long)WS_NEED);
    return;
  }
  char* ws = (char*)d_ws;
  _Float16* XP  = (_Float16*)(ws + XP_OFF);
  _Float16* AH  = (_Float16*)(ws + AH_OFF);
  _Float16* WI  = (_Float16*)(ws + WI_OFF);
  _Float16* WH  = (_Float16*)(ws + WH_OFF);
  uint32_t* THB = (uint32_t*)(ws + THB_OFF);

  k_init<<<256, 256, 0, stream>>>(h0, THB);
  k_castx<<<16384, 256, 0, stream>>>(x, AH);
  k_weights<<<8192, 256, 0, stream>>>(Wii, Wif, Wig, Wio, Whi, Whf, Whg, Who, WI, WH);
  k_gemm<<<dim3(256, 32), 256, 0, stream>>>(AH, WI, XP);
  k_rnn<<<256, 256, 0, stream>>>(XP, WH, c0, bI, bF, bG, bO, THB, out);
}